// Round 1
// baseline (79.239 us; speedup 1.0000x reference)
//
#include <hip/hip_runtime.h>

#define NQ_BLOCK 256

// N=2, DATA_DIM=16, MAX_STEPS=6 (DEPTH=5)
__global__ __launch_bounds__(NQ_BLOCK) void n3tree_query_kernel(
    const float* __restrict__ indices,   // (Q,3)
    const float* __restrict__ data,      // (n_internal*8, 16) flat
    const int*   __restrict__ child,     // (n_internal*8,) flat
    const float* __restrict__ invradius, // (3,)
    const float* __restrict__ offset,    // (3,)
    float* __restrict__ out,             // (Q,16)
    int nq)
{
    int q = blockIdx.x * NQ_BLOCK + threadIdx.x;
    if (q >= nq) return;

    const float ir0 = invradius[0], ir1 = invradius[1], ir2 = invradius[2];
    const float of0 = offset[0],    of1 = offset[1],    of2 = offset[2];

    const float hi = 1.0f - 1e-10f;
    float tx = fminf(fmaxf(indices[(size_t)q * 3 + 0] * ir0 + of0, 0.0f), hi);
    float ty = fminf(fmaxf(indices[(size_t)q * 3 + 1] * ir1 + of1, 0.0f), hi);
    float tz = fminf(fmaxf(indices[(size_t)q * 3 + 2] * ir2 + of2, 0.0f), hi);

    int node = 0;
    int leaf = 0;
    bool done = false;

#pragma unroll
    for (int s = 0; s < 6; ++s) {
        float t2x = tx * 2.0f, t2y = ty * 2.0f, t2z = tz * 2.0f;
        float flx = fminf(floorf(t2x), 1.0f);
        float fly = fminf(floorf(t2y), 1.0f);
        float flz = fminf(floorf(t2z), 1.0f);
        int ix = (int)flx, iy = (int)fly, iz = (int)flz;
        int flat = ((node * 2 + ix) * 2 + iy) * 2 + iz;
        int delta = child[flat];
        bool term = (delta == 0) && !done;
        if (term) { leaf = flat; done = true; }
        if (!done) {
            node += delta;
            tx = t2x - flx; ty = t2y - fly; tz = t2z - flz;
        }
    }

    const float4* src = reinterpret_cast<const float4*>(data + (size_t)leaf * 16);
    float4* dst = reinterpret_cast<float4*>(out + (size_t)q * 16);
    float4 d0 = src[0];
    float4 d1 = src[1];
    float4 d2 = src[2];
    float4 d3 = src[3];
    dst[0] = d0;
    dst[1] = d1;
    dst[2] = d2;
    dst[3] = d3;
}

extern "C" void kernel_launch(void* const* d_in, const int* in_sizes, int n_in,
                              void* d_out, int out_size, void* d_ws, size_t ws_size,
                              hipStream_t stream) {
    const float* indices   = (const float*)d_in[0];
    const float* data      = (const float*)d_in[1];
    const int*   child     = (const int*)d_in[2];
    const float* invradius = (const float*)d_in[3];
    const float* offset    = (const float*)d_in[4];
    float* out = (float*)d_out;

    int nq = in_sizes[0] / 3;
    int grid = (nq + NQ_BLOCK - 1) / NQ_BLOCK;
    hipLaunchKernelGGL(n3tree_query_kernel, dim3(grid), dim3(NQ_BLOCK), 0, stream,
                       indices, data, child, invradius, offset, out, nq);
}